// Round 8
// baseline (347.366 us; speedup 1.0000x reference)
//
#include <hip/hip_runtime.h>
#include <hip/hip_bf16.h>
#include <math.h>

// ScaledDotProductAttention, masked_softmax semantics (clip ±15, mask-mult,
// exp(x - max), re-mask, /(sum+1e-6)). B=16, L=2048, D=64, TEMP=8.
//
// Round-8: fix the grid-size occupancy cap (512 blk x 4 waves = only 8
// waves/CU every prior round). Now 1024 blocks x 4 waves = 16 waves/CU
// (4 blocks/CU x 40KB LDS exactly). Block = 32 q-rows = 2 wave-pairs; within
// a pair, waves split K-tiles by parity, sharing block-staged K/V LDS tiles.
// Mask nibble exchange via shfl (no LDS, no lgkm serialization); mask bits
// pass1->pass2 via 8MB ws buffer (same-thread RAW, vmcnt(0) at boundary);
// attn staged bf16 only (cvt at store); fixed shift M'=15; XCD remap.

typedef __bf16 bf16x8v __attribute__((ext_vector_type(8)));
typedef __bf16 bf16x4v __attribute__((ext_vector_type(4)));
typedef __bf16 bf16x2v __attribute__((ext_vector_type(2)));
typedef float  f32x4   __attribute__((ext_vector_type(4)));
typedef int    i32x4   __attribute__((ext_vector_type(4)));

#define B_    16
#define L_    2048
#define D_    64
#define NKC   32
#define NPAIR 16

// swizzled byte offset within a [rows][64] bf16 tile (128 B per row)
__device__ __forceinline__ int swz(int row, int colb) {
    return (row * 128 + colb) ^ ((row & 7) << 4);
}
// barrier WITHOUT vmcnt drain (prefetch loads stay in flight)
__device__ __forceinline__ void bar() {
    asm volatile("s_waitcnt lgkmcnt(0)" ::: "memory");
    __builtin_amdgcn_s_barrier();
}

template<bool UB>
__global__ __launch_bounds__(256, 4)
void sdpa_kernel(const float* __restrict__ qg,
                 const float* __restrict__ kg,
                 const float* __restrict__ vg,
                 const int*   __restrict__ mg,
                 unsigned short* __restrict__ bitws,
                 float* __restrict__ outg,    // [B][L][D]
                 float* __restrict__ attng)   // [B][L][L]
{
    __shared__ __align__(16) char KtB[2][8192];   // K tile pair bf16 [64][64] swz
    __shared__ __align__(16) char VtB[2][8192];   // V^T tile pair bf16 [d][k] swz
    __shared__ __align__(16) char PwB[4][2048];   // per-wave P bf16 [16][64] swz

    const int t  = threadIdx.x;
    const int w  = t >> 6;
    const int l  = t & 63;
    const int lq = l & 15;        // q within wave tile (MFMA col / A row)
    const int g  = l >> 4;        // 4-lane group
    const int pair = w >> 1;      // wave-pair 0..1 (16 q-rows each)
    const int par  = w & 1;       // K-tile parity this wave computes

    // XCD remap: 1024 blocks = 8 XCDs x 128 (bijective)
    const int bid  = blockIdx.x;
    const int virt = (bid & 7) * 128 + (bid >> 3);
    const int b    = virt >> 6;
    const int q0   = (virt & 63) * 32;
    const int qi   = q0 + pair * 16 + lq;

    const size_t kvbase = (size_t)b * (L_ * D_);
    const size_t qwrow  = (size_t)b * L_ + q0 + pair * 16;  // wave's first q row

    // ---- Q fragments (B operand), 1/8 temperature folded in ----
    bf16x8v qf0, qf1;
    {
        const float* qrow = qg + ((size_t)b * L_ + qi) * D_;
        const f32x4* p0 = (const f32x4*)(qrow + g * 8);
        const f32x4* p1 = (const f32x4*)(qrow + 32 + g * 8);
        f32x4 x0 = p0[0], x1 = p0[1], x2 = p1[0], x3 = p1[1];
        #pragma unroll
        for (int j = 0; j < 4; ++j) {
            qf0[j]     = (__bf16)(x0[j] * 0.125f);
            qf0[4 + j] = (__bf16)(x1[j] * 0.125f);
            qf1[j]     = (__bf16)(x2[j] * 0.125f);
            qf1[4 + j] = (__bf16)(x3[j] * 0.125f);
        }
    }

    // ---- staging geometry (whole block stages both parity tiles) ----
    const int sr  = t >> 2;               // K-tile row this thread stages
    const int scb = (t & 3) * 32;         // byte col (16 bf16 = 32 B)
    const float* kbase  = kg + kvbase + (size_t)sr * D_ + (t & 3) * 16;
    const float* vbase0 = vg + kvbase + (size_t)(2 * (t & 31)) * D_ + (t >> 5) * 8;
    const int dg = t >> 5, kp = t & 31;
    // coalesced mask producer base: rows qwrow+(l>>4)+4j, cols (l&15)*4
    const int* mbase = mg + (qwrow + (l >> 4)) * L_ + (l & 15) * 4;

    f32x4 kE[4], kO[4], vE[4], vO[4];
    i32x4 mA[4], mB[4];
    unsigned bitA = 0, bitB = 0;

    auto loadKt = [&](int kc, f32x4* r) {
        const f32x4* s = (const f32x4*)(kbase + (size_t)kc * (64 * D_));
        #pragma unroll
        for (int j = 0; j < 4; ++j) r[j] = s[j];
    };
    auto writeKt = [&](char* buf, const f32x4* r) {
        bf16x8v h0, h1;
        #pragma unroll
        for (int j = 0; j < 4; ++j) {
            h0[j] = (__bf16)r[0][j]; h0[4 + j] = (__bf16)r[1][j];
            h1[j] = (__bf16)r[2][j]; h1[4 + j] = (__bf16)r[3][j];
        }
        *(bf16x8v*)(buf + swz(sr, scb))      = h0;
        *(bf16x8v*)(buf + swz(sr, scb + 16)) = h1;
    };
    auto loadVt = [&](int kc, f32x4* r) {
        const float* r0 = vbase0 + (size_t)kc * (64 * D_);
        const f32x4* s0 = (const f32x4*)r0;
        const f32x4* s1 = (const f32x4*)(r0 + D_);
        r[0] = s0[0]; r[1] = s0[1]; r[2] = s1[0]; r[3] = s1[1];
    };
    auto writeVt = [&](char* buf, const f32x4* r) {
        #pragma unroll
        for (int j = 0; j < 4; ++j) {
            bf16x2v p0; p0[0] = (__bf16)r[0][j]; p0[1] = (__bf16)r[2][j];
            *(bf16x2v*)(buf + swz(dg * 8 + j, kp * 4)) = p0;
            bf16x2v p1; p1[0] = (__bf16)r[1][j]; p1[1] = (__bf16)r[3][j];
            *(bf16x2v*)(buf + swz(dg * 8 + 4 + j, kp * 4)) = p1;
        }
    };
    auto loadM = [&](int kc, i32x4* m) {
        const int* p = mbase + kc * 64;
        m[0] = *(const i32x4*)(p);
        m[1] = *(const i32x4*)(p + 4 * L_);
        m[2] = *(const i32x4*)(p + 8 * L_);
        m[3] = *(const i32x4*)(p + 12 * L_);
    };
    // intra-wave transpose of producer-layout mask bits -> consumer mbits
    auto xchg = [&](const i32x4* m) -> unsigned {
        auto nib = [](i32x4 v) -> unsigned {
            return (v[0] ? 1u : 0u) | (v[1] ? 2u : 0u) | (v[2] ? 4u : 0u) | (v[3] ? 8u : 0u);
        };
        unsigned packed = nib(m[0]) | (nib(m[1]) << 8) | (nib(m[2]) << 16) | (nib(m[3]) << 24);
        const int sh = (lq >> 2) * 8;
        unsigned mb = 0;
        #pragma unroll
        for (int sub = 0; sub < 4; ++sub) {
            unsigned v = (unsigned)__shfl((int)packed, (lq & 3) * 16 + sub * 4 + g, 64);
            mb |= ((v >> sh) & 0xFu) << (sub * 4);
        }
        return mb;
    };

    auto pcK = [&](int p) { return p < NPAIR ? p : NPAIR - 1; };
    auto mt  = [&](int p) { int v = 2 * p + par, mx = 2 * (NPAIR - 1) + par;
                            return v < mx ? v : mx; };
    auto bidx = [&](int kc) -> size_t {
        return ((size_t)virt * NKC + kc) * 128 + pair * 64 + l;
    };

    float rS = 0.f;
    float inv = 0.f;

    auto compute1 = [&](int kc, unsigned mbits) {
        const char* KB = KtB[par];
        if (UB) bitws[bidx(kc)] = (unsigned short)mbits;
        float part = 0.f;
        #pragma unroll
        for (int sub = 0; sub < 4; ++sub) {
            bf16x8v a0 = *(const bf16x8v*)(KB + swz(sub * 16 + lq, g * 16));
            bf16x8v a1 = *(const bf16x8v*)(KB + swz(sub * 16 + lq, 64 + g * 16));
            f32x4 s = {0.f, 0.f, 0.f, 0.f};
            s = __builtin_amdgcn_mfma_f32_16x16x32_bf16(a0, qf0, s, 0, 0, 0);
            s = __builtin_amdgcn_mfma_f32_16x16x32_bf16(a1, qf1, s, 0, 0, 0);
            #pragma unroll
            for (int r = 0; r < 4; ++r) {
                bool mm = (mbits >> (sub * 4 + r)) & 1u;
                float y = mm ? (fminf(fmaxf(s[r], -15.f), 15.f) - 15.f) : -1e30f;
                part += __expf(y);        // exp(-1e30) = 0
            }
        }
        rS += part;
    };

    f32x4 acc[4];
    #pragma unroll
    for (int i = 0; i < 4; ++i) acc[i] = (f32x4){0.f, 0.f, 0.f, 0.f};

    auto compute2 = [&](int kc, unsigned mbits) {
        const char* KB = KtB[par];
        const char* VB = VtB[par];
        #pragma unroll
        for (int sub = 0; sub < 4; ++sub) {
            bf16x8v a0 = *(const bf16x8v*)(KB + swz(sub * 16 + lq, g * 16));
            bf16x8v a1 = *(const bf16x8v*)(KB + swz(sub * 16 + lq, 64 + g * 16));
            f32x4 s = {0.f, 0.f, 0.f, 0.f};
            s = __builtin_amdgcn_mfma_f32_16x16x32_bf16(a0, qf0, s, 0, 0, 0);
            s = __builtin_amdgcn_mfma_f32_16x16x32_bf16(a1, qf1, s, 0, 0, 0);
            bf16x4v pb;
            #pragma unroll
            for (int r = 0; r < 4; ++r) {
                bool mm = (mbits >> (sub * 4 + r)) & 1u;
                float y = mm ? (fminf(fmaxf(s[r], -15.f), 15.f) - 15.f) : -1e30f;
                pb[r] = (__bf16)(__expf(y) * inv);
            }
            *(bf16x4v*)(PwB[w] + swz(lq, (sub * 16 + g * 4) * 2)) = pb;
        }
        // PV MFMAs (same-wave LDS RAW)
        #pragma unroll
        for (int ks = 0; ks < 2; ++ks) {
            bf16x8v pa = *(const bf16x8v*)(PwB[w] + swz(lq, ks * 64 + g * 16));
            #pragma unroll
            for (int dt = 0; dt < 4; ++dt) {
                bf16x8v vb = *(const bf16x8v*)(VB + swz(dt * 16 + lq, ks * 64 + g * 16));
                acc[dt] = __builtin_amdgcn_mfma_f32_16x16x32_bf16(pa, vb, acc[dt], 0, 0, 0);
            }
        }
        // coalesced attn store: 4 instrs x (4 rows x 256 B contiguous)
        #pragma unroll
        for (int j = 0; j < 4; ++j) {
            const int row = (l >> 4) + 4 * j;
            const int col = (l & 15) * 4;
            bf16x4v pq = *(const bf16x4v*)(PwB[w] + swz(row, col * 2));
            f32x4 o;
            #pragma unroll
            for (int c = 0; c < 4; ++c) o[c] = (float)pq[c];
            *(f32x4*)(attng + (qwrow + row) * L_ + kc * 64 + col) = o;
        }
    };

    // ======================= PASS 1: masked exp-sum =======================
    loadKt(0, kE); loadKt(1, kO);
    loadM(mt(0), mA);
    writeKt(KtB[0], kE); writeKt(KtB[1], kO);
    loadM(mt(1), mB);
    loadKt(2, kE); loadKt(3, kO);
    bar();
    #pragma unroll 1
    for (int i = 0; i < NPAIR; i += 2) {
        compute1(2 * i + par, xchg(mA));
        bar();
        writeKt(KtB[0], kE); writeKt(KtB[1], kO);        // pair i+1
        loadKt(2 * pcK(i + 2), kE); loadKt(2 * pcK(i + 2) + 1, kO);
        loadM(mt(i + 2), mA);
        bar();
        compute1(2 * (i + 1) + par, xchg(mB));
        bar();
        writeKt(KtB[0], kE); writeKt(KtB[1], kO);        // pair i+2
        loadKt(2 * pcK(i + 3), kE); loadKt(2 * pcK(i + 3) + 1, kO);
        loadM(mt(i + 3), mB);
        bar();
    }

    // reduce within wave, then combine parity partners' sums via LDS
    rS += __shfl_xor(rS, 16, 64);
    rS += __shfl_xor(rS, 32, 64);
    asm volatile("s_waitcnt vmcnt(0)" ::: "memory");     // bits landed (UB)
    {
        float* sx = (float*)(PwB[0]);
        if (l < 16) sx[w * 16 + l] = rS;
        bar();
        float oth = sx[(pair * 2 + (1 - par)) * 16 + lq];
        inv = 1.f / (rS + oth + 1e-6f);
        bar();                                           // sx read done
    }

    // ======================= PASS 2: attn + PV =======================
    loadKt(0, kE); loadKt(1, kO);
    loadVt(0, vE); loadVt(1, vO);
    if (UB) bitA = bitws[bidx(mt(0))]; else loadM(mt(0), mA);
    writeKt(KtB[0], kE); writeKt(KtB[1], kO);
    writeVt(VtB[0], vE); writeVt(VtB[1], vO);
    if (UB) bitB = bitws[bidx(mt(1))]; else loadM(mt(1), mB);
    loadKt(2, kE); loadKt(3, kO);
    loadVt(2, vE); loadVt(3, vO);
    bar();
    #pragma unroll 1
    for (int i = 0; i < NPAIR; i += 2) {
        compute2(2 * i + par, UB ? bitA : xchg(mA));
        bar();
        writeKt(KtB[0], kE); writeKt(KtB[1], kO);
        writeVt(VtB[0], vE); writeVt(VtB[1], vO);
        loadKt(2 * pcK(i + 2), kE); loadKt(2 * pcK(i + 2) + 1, kO);
        loadVt(2 * pcK(i + 2), vE); loadVt(2 * pcK(i + 2) + 1, vO);
        if (UB) bitA = bitws[bidx(mt(i + 2))]; else loadM(mt(i + 2), mA);
        bar();
        compute2(2 * (i + 1) + par, UB ? bitB : xchg(mB));
        bar();
        writeKt(KtB[0], kE); writeKt(KtB[1], kO);
        writeVt(VtB[0], vE); writeVt(VtB[1], vO);
        loadKt(2 * pcK(i + 3), kE); loadKt(2 * pcK(i + 3) + 1, kO);
        loadVt(2 * pcK(i + 3), vE); loadVt(2 * pcK(i + 3) + 1, vO);
        if (UB) bitB = bitws[bidx(mt(i + 3))]; else loadM(mt(i + 3), mB);
        bar();
    }

    // ---- combine partial O across the parity pair (reuse KtB as f32 buf) ----
    float* ob = (float*)(KtB[0]) + pair * 1088;          // 16 rows x 68 f32
    if (par == 1) {
        #pragma unroll
        for (int dt = 0; dt < 4; ++dt)
            #pragma unroll
            for (int r = 0; r < 4; ++r)
                ob[(g * 4 + r) * 68 + dt * 16 + lq] = acc[dt][r];
    }
    bar();
    if (par == 0) {
        #pragma unroll
        for (int dt = 0; dt < 4; ++dt)
            #pragma unroll
            for (int r = 0; r < 4; ++r) {
                float o = acc[dt][r] + ob[(g * 4 + r) * 68 + dt * 16 + lq];
                outg[(qwrow + g * 4 + r) * D_ + dt * 16 + lq] = o;
            }
    }
}

extern "C" void kernel_launch(void* const* d_in, const int* in_sizes, int n_in,
                              void* d_out, int out_size, void* d_ws, size_t ws_size,
                              hipStream_t stream) {
    (void)in_sizes; (void)n_in; (void)out_size;
    const float* q = (const float*)d_in[0];
    const float* k = (const float*)d_in[1];
    const float* v = (const float*)d_in[2];
    const int*   m = (const int*)d_in[3];
    float* out  = (float*)d_out;
    float* attn = out + (size_t)B_ * L_ * D_;
    unsigned short* bitws = (unsigned short*)d_ws;
    const size_t need = (size_t)1024 * NKC * 128 * sizeof(unsigned short); // 8 MB

    dim3 grid(1024), block(256);
    if (ws_size >= need) {
        hipLaunchKernelGGL((sdpa_kernel<true>),  grid, block, 0, stream,
                           q, k, v, m, bitws, out, attn);
    } else {
        hipLaunchKernelGGL((sdpa_kernel<false>), grid, block, 0, stream,
                           q, k, v, m, (unsigned short*)nullptr, out, attn);
    }
}

// Round 9
// 188.321 us; speedup vs baseline: 1.8445x; 1.8445x over previous
//
#include <hip/hip_runtime.h>
#include <hip/hip_bf16.h>
#include <math.h>

// ScaledDotProductAttention, masked_softmax semantics (clip ±15, mask-mult,
// exp(x - max), re-mask, /(sum+1e-6)). B=16, L=2048, D=64, TEMP=8.
//
// Round-9: R7's skeleton (512 blocks, 64 q-rows/block, fixed shift M'=15,
// swizzled LDS, coalesced mask load + shfl bit-transpose, coalesced attn
// store, lgkm-only barriers, XCD remap) widened to 512 threads / 8 waves:
// wave = (q-group 0..3, k-half 0..1); each wave owns 16 q-rows x contiguous
// 1024 k (sequential per-wave mask/attn streams). 16 waves/CU (2 blocks x
// 8 waves), double R7. Mask bits pass1->pass2 in LDS (same thread). No ws.

typedef __bf16 bf16x8v __attribute__((ext_vector_type(8)));
typedef __bf16 bf16x4v __attribute__((ext_vector_type(4)));
typedef __bf16 bf16x2v __attribute__((ext_vector_type(2)));
typedef float  f32x4   __attribute__((ext_vector_type(4)));
typedef int    i32x4   __attribute__((ext_vector_type(4)));

#define B_  16
#define L_  2048
#define D_  64
#define NH  16     // tiles per k-half

// swizzled byte offset within a [rows][64] bf16 tile (128 B per row)
__device__ __forceinline__ int swz(int row, int colb) {
    return (row * 128 + colb) ^ ((row & 7) << 4);
}
// barrier WITHOUT vmcnt drain (prefetch loads stay in flight)
__device__ __forceinline__ void bar() {
    asm volatile("s_waitcnt lgkmcnt(0)" ::: "memory");
    __builtin_amdgcn_s_barrier();
}

__global__ __launch_bounds__(512, 4)
void sdpa_kernel(const float* __restrict__ qg,
                 const float* __restrict__ kg,
                 const float* __restrict__ vg,
                 const int*   __restrict__ mg,
                 float* __restrict__ outg,    // [B][L][D]
                 float* __restrict__ attng)   // [B][L][L]
{
    // arena: Kt[2][8192] | Vt[2][8192] | Pw[8][2048] | Ml u16[16][512] | sxb f32[8][16]
    __shared__ __align__(16) char arena[66048];
    char* KtH = arena;                      // per-half K tile
    char* VtH = arena + 16384;              // per-half V^T tile
    char* PwA = arena + 32768;              // per-wave P bf16 [16][64] swz
    unsigned short* Ml = (unsigned short*)(arena + 49152);
    float* sxb = (float*)(arena + 65536);

    const int t    = threadIdx.x;
    const int w    = t >> 6;       // wave 0..7
    const int l    = t & 63;
    const int lq   = l & 15;       // q within wave tile (MFMA col / A row)
    const int g    = l >> 4;       // 4-lane group
    const int qgp  = w >> 1;       // q-group 0..3 (16 rows each)
    const int half = w & 1;        // k-half 0..1 (contiguous 1024 k)

    // XCD remap: 512 blocks = 8 XCDs x 64 (bijective)
    const int bid  = blockIdx.x;
    const int virt = (bid & 7) * 64 + (bid >> 3);
    const int b    = virt >> 5;
    const int q0   = (virt & 31) * 64;
    const int qi   = q0 + qgp * 16 + lq;

    const size_t kvbase = (size_t)b * (L_ * D_);
    const size_t qwrow  = (size_t)b * L_ + q0 + qgp * 16;   // wave's first q row

    // ---- Q fragments (B operand), 1/8 temperature folded in ----
    bf16x8v qf0, qf1;
    {
        const float* qrow = qg + ((size_t)b * L_ + qi) * D_;
        const f32x4* p0 = (const f32x4*)(qrow + g * 8);
        const f32x4* p1 = (const f32x4*)(qrow + 32 + g * 8);
        f32x4 x0 = p0[0], x1 = p0[1], x2 = p1[0], x3 = p1[1];
        #pragma unroll
        for (int j = 0; j < 4; ++j) {
            qf0[j]     = (__bf16)(x0[j] * 0.125f);
            qf0[4 + j] = (__bf16)(x1[j] * 0.125f);
            qf1[j]     = (__bf16)(x2[j] * 0.125f);
            qf1[4 + j] = (__bf16)(x3[j] * 0.125f);
        }
    }

    // ---- staging geometry: threads <256 stage half 0, >=256 stage half 1 ----
    const int sh  = t >> 8;               // staging half
    const int st  = t & 255;
    const int sr  = st >> 2;              // K-tile row
    const int scb = (st & 3) * 32;        // byte col (16 bf16)
    const float* kbase  = kg + kvbase + (size_t)(sh * 1024 + sr) * D_ + (st & 3) * 16;
    const int kp = st & 31, dg = st >> 5;
    const float* vbase0 = vg + kvbase + (size_t)(sh * 1024 + 2 * kp) * D_ + dg * 8;
    char* KtS = KtH + sh * 8192;
    char* VtS = VtH + sh * 8192;
    // per-wave coalesced mask base: rows qwrow+(l>>4)+4j, cols half*1024+(l&15)*4
    const int* mbase = mg + (qwrow + (l >> 4)) * L_ + half * 1024 + (l & 15) * 4;

    f32x4 kr[4], vr[4];
    i32x4 mr[4];

    auto loadK = [&](int i) {
        const f32x4* s = (const f32x4*)(kbase + (size_t)i * (64 * D_));
        #pragma unroll
        for (int j = 0; j < 4; ++j) kr[j] = s[j];
    };
    auto writeK = [&]() {
        bf16x8v h0, h1;
        #pragma unroll
        for (int j = 0; j < 4; ++j) {
            h0[j] = (__bf16)kr[0][j]; h0[4 + j] = (__bf16)kr[1][j];
            h1[j] = (__bf16)kr[2][j]; h1[4 + j] = (__bf16)kr[3][j];
        }
        *(bf16x8v*)(KtS + swz(sr, scb))      = h0;
        *(bf16x8v*)(KtS + swz(sr, scb + 16)) = h1;
    };
    auto loadV = [&](int i) {
        const float* r0 = vbase0 + (size_t)i * (64 * D_);
        const f32x4* s0 = (const f32x4*)r0;
        const f32x4* s1 = (const f32x4*)(r0 + D_);
        vr[0] = s0[0]; vr[1] = s0[1]; vr[2] = s1[0]; vr[3] = s1[1];
    };
    auto writeV = [&]() {
        #pragma unroll
        for (int j = 0; j < 4; ++j) {
            bf16x2v p0; p0[0] = (__bf16)vr[0][j]; p0[1] = (__bf16)vr[2][j];
            *(bf16x2v*)(VtS + swz(dg * 8 + j, kp * 4)) = p0;
            bf16x2v p1; p1[0] = (__bf16)vr[1][j]; p1[1] = (__bf16)vr[3][j];
            *(bf16x2v*)(VtS + swz(dg * 8 + 4 + j, kp * 4)) = p1;
        }
    };
    auto loadM = [&](int i) {
        const int* p = mbase + i * 64;
        mr[0] = *(const i32x4*)(p);
        mr[1] = *(const i32x4*)(p + 4 * L_);
        mr[2] = *(const i32x4*)(p + 8 * L_);
        mr[3] = *(const i32x4*)(p + 12 * L_);
    };
    // intra-wave transpose: producer rows (l>>4)+4j / cols (l&15)*4 -> consumer bits
    auto xchg = [&]() -> unsigned {
        auto nib = [](i32x4 v) -> unsigned {
            return (v[0] ? 1u : 0u) | (v[1] ? 2u : 0u) | (v[2] ? 4u : 0u) | (v[3] ? 8u : 0u);
        };
        unsigned packed = nib(mr[0]) | (nib(mr[1]) << 8) | (nib(mr[2]) << 16) | (nib(mr[3]) << 24);
        const int shl = (lq >> 2) * 8;
        unsigned mb = 0;
        #pragma unroll
        for (int sub = 0; sub < 4; ++sub) {
            unsigned v = (unsigned)__shfl((int)packed, (lq & 3) * 16 + sub * 4 + g, 64);
            mb |= ((v >> shl) & 0xFu) << (sub * 4);
        }
        return mb;
    };
    auto clampI = [](int i) { return i < NH ? i : NH - 1; };

    const char* KB = KtH + half * 8192;   // wave's compute tiles
    const char* VB = VtH + half * 8192;
    char* PW = PwA + w * 2048;

    float rS = 0.f;
    float inv = 0.f;

    // ======================= PASS 1: masked exp-sum =======================
    loadK(0); loadM(0);
    writeK();                               // one-time stall
    loadK(1);
    unsigned mb = xchg();
    loadM(1);
    bar();
    #pragma unroll 1
    for (int i = 0; i < NH; ++i) {
        // compute tile i (LDS), bits mb
        Ml[i * 512 + t] = (unsigned short)mb;
        float part = 0.f;
        #pragma unroll
        for (int sub = 0; sub < 4; ++sub) {
            bf16x8v a0 = *(const bf16x8v*)(KB + swz(sub * 16 + lq, g * 16));
            bf16x8v a1 = *(const bf16x8v*)(KB + swz(sub * 16 + lq, 64 + g * 16));
            f32x4 s = {0.f, 0.f, 0.f, 0.f};
            s = __builtin_amdgcn_mfma_f32_16x16x32_bf16(a0, qf0, s, 0, 0, 0);
            s = __builtin_amdgcn_mfma_f32_16x16x32_bf16(a1, qf1, s, 0, 0, 0);
            #pragma unroll
            for (int r = 0; r < 4; ++r) {
                bool mm = (mb >> (sub * 4 + r)) & 1u;
                float y = mm ? (fminf(fmaxf(s[r], -15.f), 15.f) - 15.f) : -1e30f;
                part += __expf(y);          // exp(-1e30) = 0
            }
        }
        rS += part;
        unsigned mbN = xchg();              // bits for tile i+1
        loadM(clampI(i + 2));
        bar();                              // readers done with tile i
        writeK();                           // tile i+1 (regs loaded last iter)
        loadK(clampI(i + 2));
        bar();                              // tile i+1 visible
        mb = mbN;
    }

    // ---- combine the two k-halves' sums per q-group ----
    rS += __shfl_xor(rS, 16, 64);
    rS += __shfl_xor(rS, 32, 64);
    loadK(0); loadV(0);                     // pass-2 prefetch overlaps exchange
    if (l < 16) sxb[w * 16 + l] = rS;
    bar();
    inv = 1.f / (rS + sxb[(w ^ 1) * 16 + lq] + 1e-6f);

    // ======================= PASS 2: attn + PV =======================
    f32x4 acc[4];
    #pragma unroll
    for (int i = 0; i < 4; ++i) acc[i] = (f32x4){0.f, 0.f, 0.f, 0.f};

    writeK(); writeV();                     // tiles 0 (stall once)
    loadK(1); loadV(1);
    bar();
    #pragma unroll 1
    for (int i = 0; i < NH; ++i) {
        const unsigned mbits = Ml[i * 512 + t];
        const int kc = half * NH + i;
        #pragma unroll
        for (int sub = 0; sub < 4; ++sub) {
            bf16x8v a0 = *(const bf16x8v*)(KB + swz(sub * 16 + lq, g * 16));
            bf16x8v a1 = *(const bf16x8v*)(KB + swz(sub * 16 + lq, 64 + g * 16));
            f32x4 s = {0.f, 0.f, 0.f, 0.f};
            s = __builtin_amdgcn_mfma_f32_16x16x32_bf16(a0, qf0, s, 0, 0, 0);
            s = __builtin_amdgcn_mfma_f32_16x16x32_bf16(a1, qf1, s, 0, 0, 0);
            bf16x4v pb;
            #pragma unroll
            for (int r = 0; r < 4; ++r) {
                bool mm = (mbits >> (sub * 4 + r)) & 1u;
                float y = mm ? (fminf(fmaxf(s[r], -15.f), 15.f) - 15.f) : -1e30f;
                pb[r] = (__bf16)(__expf(y) * inv);
            }
            *(bf16x4v*)(PW + swz(lq, (sub * 16 + g * 4) * 2)) = pb;
        }
        // PV MFMAs (same-wave LDS RAW)
        #pragma unroll
        for (int ks = 0; ks < 2; ++ks) {
            bf16x8v pa = *(const bf16x8v*)(PW + swz(lq, ks * 64 + g * 16));
            #pragma unroll
            for (int dt = 0; dt < 4; ++dt) {
                bf16x8v vb = *(const bf16x8v*)(VB + swz(dt * 16 + lq, ks * 64 + g * 16));
                acc[dt] = __builtin_amdgcn_mfma_f32_16x16x32_bf16(pa, vb, acc[dt], 0, 0, 0);
            }
        }
        // coalesced attn store: 4 instrs x (4 rows x 256 B contiguous)
        #pragma unroll
        for (int j = 0; j < 4; ++j) {
            const int row = (l >> 4) + 4 * j;
            const int col = (l & 15) * 4;
            bf16x4v pq = *(const bf16x4v*)(PW + swz(row, col * 2));
            f32x4 o;
            #pragma unroll
            for (int c = 0; c < 4; ++c) o[c] = (float)pq[c];
            *(f32x4*)(attng + (qwrow + row) * L_ + kc * 64 + col) = o;
        }
        bar();                              // readers done with tile i
        writeK(); writeV();                 // tiles i+1
        loadK(clampI(i + 2)); loadV(clampI(i + 2));
        bar();                              // tiles i+1 visible
    }

    // ---- combine partial O across the two k-halves (arena reuse) ----
    float* ob = (float*)arena + qgp * 1088;    // 16 rows x 68 f32
    if (half == 1) {
        #pragma unroll
        for (int dt = 0; dt < 4; ++dt)
            #pragma unroll
            for (int r = 0; r < 4; ++r)
                ob[(g * 4 + r) * 68 + dt * 16 + lq] = acc[dt][r];
    }
    bar();
    if (half == 0) {
        #pragma unroll
        for (int dt = 0; dt < 4; ++dt)
            #pragma unroll
            for (int r = 0; r < 4; ++r) {
                float o = acc[dt][r] + ob[(g * 4 + r) * 68 + dt * 16 + lq];
                outg[(qwrow + g * 4 + r) * D_ + dt * 16 + lq] = o;
            }
    }
}

extern "C" void kernel_launch(void* const* d_in, const int* in_sizes, int n_in,
                              void* d_out, int out_size, void* d_ws, size_t ws_size,
                              hipStream_t stream) {
    (void)in_sizes; (void)n_in; (void)out_size; (void)d_ws; (void)ws_size;
    const float* q = (const float*)d_in[0];
    const float* k = (const float*)d_in[1];
    const float* v = (const float*)d_in[2];
    const int*   m = (const int*)d_in[3];
    float* out  = (float*)d_out;
    float* attn = out + (size_t)B_ * L_ * D_;
    dim3 grid(B_ * (L_ / 64));   // 512
    dim3 block(512);
    hipLaunchKernelGGL(sdpa_kernel, grid, block, 0, stream, q, k, v, m, out, attn);
}

// Round 10
// 182.554 us; speedup vs baseline: 1.9028x; 1.0316x over previous
//
#include <hip/hip_runtime.h>
#include <hip/hip_bf16.h>
#include <math.h>

// ScaledDotProductAttention, masked_softmax semantics (clip ±15, mask-mult,
// exp(x - max), re-mask, /(sum+1e-6)). B=16, L=2048, D=64, TEMP=8.
//
// Round-10 = R7 skeleton (512 blocks x 4 waves, wave = 16 q-rows x all k,
// fixed shift M'=15, dbuf swizzled K/V LDS, coalesced mask load + shfl bit
// transpose, lgkm-only barriers, XCD remap) + WRITE AGGREGATION:
// P for 4 consecutive k-tiles (256 k) accumulates in a per-wave LDS tile
// [16][256] bf16; attn is flushed as 16 rows x 1KB contiguous f32 stores
// (vs 256B/row/tile scatter). Theory: scattered 256B row-chunks collapse
// DRAM write page locality (all kernels pin at ~1.7 TB/s write while
// fillBuffer does 6.8); 1KB bursts should recover 2-4x write efficiency.

typedef __bf16 bf16x8v __attribute__((ext_vector_type(8)));
typedef __bf16 bf16x4v __attribute__((ext_vector_type(4)));
typedef __bf16 bf16x2v __attribute__((ext_vector_type(2)));
typedef float  f32x4   __attribute__((ext_vector_type(4)));
typedef int    i32x4   __attribute__((ext_vector_type(4)));

#define B_  16
#define L_  2048
#define D_  64
#define NKC 32

// swizzled byte offset within a [rows][64] bf16 tile (128 B per row)
__device__ __forceinline__ int swz(int row, int colb) {
    return (row * 128 + colb) ^ ((row & 7) << 4);
}
// barrier WITHOUT vmcnt drain (prefetch loads stay in flight)
__device__ __forceinline__ void bar() {
    asm volatile("s_waitcnt lgkmcnt(0)" ::: "memory");
    __builtin_amdgcn_s_barrier();
}

__global__ __launch_bounds__(256, 2)
void sdpa_kernel(const float* __restrict__ qg,
                 const float* __restrict__ kg,
                 const float* __restrict__ vg,
                 const int*   __restrict__ mg,
                 float* __restrict__ outg,    // [B][L][D]
                 float* __restrict__ attng)   // [B][L][L]
{
    // 80KB arena: Kt dbuf 16K | Vt dbuf 16K | Pacc 4x8K | Ml u16 16K
    __shared__ __align__(16) char arena[81920];
    char* KtB0 = arena;
    char* KtB1 = arena + 8192;
    char* VtB0 = arena + 16384;
    char* VtB1 = arena + 24576;
    char* Pacc = arena + 32768;                       // [wave][16 q][256 k] bf16 swz
    unsigned short* Ml = (unsigned short*)(arena + 65536);  // [kc][thread]

    const int t  = threadIdx.x;
    const int w  = t >> 6;
    const int l  = t & 63;
    const int lq = l & 15;        // q within wave tile (MFMA col / A row)
    const int g  = l >> 4;        // 4-lane group

    // XCD remap: 512 blocks = 8 XCDs x 64 (bijective)
    const int bid  = blockIdx.x;
    const int virt = (bid & 7) * 64 + (bid >> 3);
    const int b  = virt >> 5;
    const int q0 = (virt & 31) * 64;
    const int qi = q0 + w * 16 + lq;

    const size_t kvbase = (size_t)b * (L_ * D_);
    const size_t qwrow  = (size_t)b * L_ + q0 + w * 16;  // wave's first q row

    // ---- Q fragments (B operand), 1/8 temperature folded in ----
    bf16x8v qf0, qf1;
    {
        const float* qrow = qg + ((size_t)b * L_ + qi) * D_;
        const f32x4* p0 = (const f32x4*)(qrow + g * 8);
        const f32x4* p1 = (const f32x4*)(qrow + 32 + g * 8);
        f32x4 x0 = p0[0], x1 = p0[1], x2 = p1[0], x3 = p1[1];
        #pragma unroll
        for (int j = 0; j < 4; ++j) {
            qf0[j]     = (__bf16)(x0[j] * 0.125f);
            qf0[4 + j] = (__bf16)(x1[j] * 0.125f);
            qf1[j]     = (__bf16)(x2[j] * 0.125f);
            qf1[4 + j] = (__bf16)(x3[j] * 0.125f);
        }
    }

    // ---- staging geometry ----
    const int sr  = t >> 2;               // K-tile row this thread stages
    const int scb = (t & 3) * 32;         // byte col (16 bf16 = 32 B)
    const float* kbase  = kg + kvbase + (size_t)sr * D_ + (t & 3) * 16;
    const float* vbase0 = vg + kvbase + (size_t)(2 * (t & 31)) * D_ + (t >> 5) * 8;
    const int dg = t >> 5, kp = t & 31;
    // coalesced mask producer base: rows qwrow+(l>>4)+4j, cols (l&15)*4
    const int* mbase = mg + (qwrow + (l >> 4)) * L_ + (l & 15) * 4;

    auto loadK = [&](int kc, f32x4* r) {
        const f32x4* s = (const f32x4*)(kbase + (size_t)kc * (64 * D_));
        #pragma unroll
        for (int j = 0; j < 4; ++j) r[j] = s[j];
    };
    auto writeK = [&](char* buf, const f32x4* r) {
        bf16x8v h0, h1;
        #pragma unroll
        for (int j = 0; j < 4; ++j) {
            h0[j] = (__bf16)r[0][j]; h0[4 + j] = (__bf16)r[1][j];
            h1[j] = (__bf16)r[2][j]; h1[4 + j] = (__bf16)r[3][j];
        }
        *(bf16x8v*)(buf + swz(sr, scb))      = h0;
        *(bf16x8v*)(buf + swz(sr, scb + 16)) = h1;
    };
    auto loadV = [&](int kc, f32x4* r) {
        const float* r0 = vbase0 + (size_t)kc * (64 * D_);
        const f32x4* s0 = (const f32x4*)r0;
        const f32x4* s1 = (const f32x4*)(r0 + D_);
        r[0] = s0[0]; r[1] = s0[1]; r[2] = s1[0]; r[3] = s1[1];
    };
    auto writeV = [&](char* buf, const f32x4* r) {
        #pragma unroll
        for (int j = 0; j < 4; ++j) {
            bf16x2v p0; p0[0] = (__bf16)r[0][j]; p0[1] = (__bf16)r[2][j];
            *(bf16x2v*)(buf + swz(dg * 8 + j, kp * 4)) = p0;
            bf16x2v p1; p1[0] = (__bf16)r[1][j]; p1[1] = (__bf16)r[3][j];
            *(bf16x2v*)(buf + swz(dg * 8 + 4 + j, kp * 4)) = p1;
        }
    };
    auto loadM = [&](int kc, i32x4* m) {
        const int* p = mbase + kc * 64;
        m[0] = *(const i32x4*)(p);
        m[1] = *(const i32x4*)(p + 4 * L_);
        m[2] = *(const i32x4*)(p + 8 * L_);
        m[3] = *(const i32x4*)(p + 12 * L_);
    };
    // intra-wave transpose of producer-layout mask bits -> consumer mbits
    auto xchg = [&](const i32x4* m) -> unsigned {
        auto nib = [](i32x4 v) -> unsigned {
            return (v[0] ? 1u : 0u) | (v[1] ? 2u : 0u) | (v[2] ? 4u : 0u) | (v[3] ? 8u : 0u);
        };
        unsigned packed = nib(m[0]) | (nib(m[1]) << 8) | (nib(m[2]) << 16) | (nib(m[3]) << 24);
        const int sh = (lq >> 2) * 8;
        unsigned mb = 0;
        #pragma unroll
        for (int sub = 0; sub < 4; ++sub) {
            unsigned v = (unsigned)__shfl((int)packed, (lq & 3) * 16 + sub * 4 + g, 64);
            mb |= ((v >> sh) & 0xFu) << (sub * 4);
        }
        return mb;
    };

    float rS = 0.f;
    float inv = 0.f;
    char* PW = Pacc + w * 8192;

    auto compute1 = [&](const char* KB, int kc, unsigned mbits) {
        Ml[kc * 256 + t] = (unsigned short)mbits;
        float part = 0.f;
        #pragma unroll
        for (int sub = 0; sub < 4; ++sub) {
            bf16x8v a0 = *(const bf16x8v*)(KB + swz(sub * 16 + lq, g * 16));
            bf16x8v a1 = *(const bf16x8v*)(KB + swz(sub * 16 + lq, 64 + g * 16));
            f32x4 s = {0.f, 0.f, 0.f, 0.f};
            s = __builtin_amdgcn_mfma_f32_16x16x32_bf16(a0, qf0, s, 0, 0, 0);
            s = __builtin_amdgcn_mfma_f32_16x16x32_bf16(a1, qf1, s, 0, 0, 0);
            #pragma unroll
            for (int r = 0; r < 4; ++r) {
                bool mm = (mbits >> (sub * 4 + r)) & 1u;
                float y = mm ? (fminf(fmaxf(s[r], -15.f), 15.f) - 15.f) : -1e30f;
                part += __expf(y);        // exp(-1e30) = 0
            }
        }
        rS += part;
    };

    f32x4 acc[4];
    #pragma unroll
    for (int i = 0; i < 4; ++i) acc[i] = (f32x4){0.f, 0.f, 0.f, 0.f};

    auto compute2 = [&](const char* KB, const char* VB, int kc) {
        const unsigned mbits = Ml[kc * 256 + t];
        const int tt = kc & 3;
        #pragma unroll
        for (int sub = 0; sub < 4; ++sub) {
            bf16x8v a0 = *(const bf16x8v*)(KB + swz(sub * 16 + lq, g * 16));
            bf16x8v a1 = *(const bf16x8v*)(KB + swz(sub * 16 + lq, 64 + g * 16));
            f32x4 s = {0.f, 0.f, 0.f, 0.f};
            s = __builtin_amdgcn_mfma_f32_16x16x32_bf16(a0, qf0, s, 0, 0, 0);
            s = __builtin_amdgcn_mfma_f32_16x16x32_bf16(a1, qf1, s, 0, 0, 0);
            bf16x4v pb;
            #pragma unroll
            for (int r = 0; r < 4; ++r) {
                bool mm = (mbits >> (sub * 4 + r)) & 1u;
                float y = mm ? (fminf(fmaxf(s[r], -15.f), 15.f) - 15.f) : -1e30f;
                pb[r] = (__bf16)(__expf(y) * inv);
            }
            *(bf16x4v*)(PW + lq * 512 + ((tt * 128 + sub * 32 + g * 8) ^ ((lq & 7) << 4))) = pb;
        }
        // PV MFMAs: A-fragments straight from the Pacc slice (same-wave RAW)
        #pragma unroll
        for (int ks = 0; ks < 2; ++ks) {
            bf16x8v pa = *(const bf16x8v*)(PW + lq * 512 +
                                           ((tt * 128 + ks * 64 + g * 16) ^ ((lq & 7) << 4)));
            #pragma unroll
            for (int dt = 0; dt < 4; ++dt) {
                bf16x8v vb = *(const bf16x8v*)(VB + swz(dt * 16 + lq, ks * 64 + g * 16));
                acc[dt] = __builtin_amdgcn_mfma_f32_16x16x32_bf16(pa, vb, acc[dt], 0, 0, 0);
            }
        }
    };

    // flush one super-chunk (4 tiles, 256 k): 16 rows x 1KB contiguous stores
    auto flushA = [&](int sc) {
        #pragma unroll
        for (int r = 0; r < 16; ++r) {
            bf16x4v pq = *(const bf16x4v*)(PW + r * 512 + ((l * 8) ^ ((r & 7) << 4)));
            f32x4 o;
            #pragma unroll
            for (int c = 0; c < 4; ++c) o[c] = (float)pq[c];
            *(f32x4*)(attng + (qwrow + r) * L_ + sc * 256 + l * 4) = o;
        }
    };

    // prefetch register sets (A = even tiles, B = odd tiles)
    f32x4 kA[4], kB[4], vA[4], vB[4];
    i32x4 mA[4], mB[4];

    // ======================= PASS 1: masked exp-sum =======================
    loadK(0, kA);
    loadM(0, mA);
    writeK(KtB0, kA);                        // one-time stall
    loadK(1, kB);
    loadM(1, mB);
    bar();
    #pragma unroll 1
    for (int kc = 0; kc < NKC; kc += 2) {
        { int kn = (kc + 2 < NKC) ? kc + 2 : NKC - 1; loadK(kn, kA); }
        { unsigned mb = xchg(mA);
          { int kn = (kc + 2 < NKC) ? kc + 2 : NKC - 1; loadM(kn, mA); }
          compute1(KtB0, kc, mb); }
        writeK(KtB1, kB);                    // tile kc+1 (regs from last iter)
        bar();
        { int kn = (kc + 3 < NKC) ? kc + 3 : NKC - 1; loadK(kn, kB); }
        { unsigned mb = xchg(mB);
          { int kn = (kc + 3 < NKC) ? kc + 3 : NKC - 1; loadM(kn, mB); }
          compute1(KtB1, kc + 1, mb); }
        writeK(KtB0, kA);                    // tile kc+2
        bar();
    }

    // issue pass-2 first tiles, then reduce (overlap load latency)
    loadK(0, kA);
    loadV(0, vA);
    rS += __shfl_xor(rS, 16, 64);
    rS += __shfl_xor(rS, 32, 64);
    inv = 1.f / (rS + 1e-6f);

    // ======================= PASS 2: attn + PV =======================
    writeK(KtB0, kA);
    writeV(VtB0, vA);
    loadK(1, kB);
    loadV(1, vB);
    bar();
    #pragma unroll 1
    for (int kc = 0; kc < NKC; kc += 2) {
        { int kn = (kc + 2 < NKC) ? kc + 2 : NKC - 1; loadK(kn, kA); loadV(kn, vA); }
        compute2(KtB0, VtB0, kc);
        writeK(KtB1, kB);
        writeV(VtB1, vB);
        bar();
        { int kn = (kc + 3 < NKC) ? kc + 3 : NKC - 1; loadK(kn, kB); loadV(kn, vB); }
        compute2(KtB1, VtB1, kc + 1);
        if ((kc & 3) == 2) flushA((kc + 1) >> 2);   // tiles sc*4..sc*4+3 done
        writeK(KtB0, kA);
        writeV(VtB0, vA);
        bar();
    }

    // epilogue: acc row = q-local (g*4+r), col = d (dt*16+lq)
    #pragma unroll
    for (int dt = 0; dt < 4; ++dt) {
        #pragma unroll
        for (int r = 0; r < 4; ++r) {
            outg[(qwrow + g * 4 + r) * D_ + dt * 16 + lq] = acc[dt][r];
        }
    }
}

extern "C" void kernel_launch(void* const* d_in, const int* in_sizes, int n_in,
                              void* d_out, int out_size, void* d_ws, size_t ws_size,
                              hipStream_t stream) {
    (void)in_sizes; (void)n_in; (void)out_size; (void)d_ws; (void)ws_size;
    const float* q = (const float*)d_in[0];
    const float* k = (const float*)d_in[1];
    const float* v = (const float*)d_in[2];
    const int*   m = (const int*)d_in[3];
    float* out  = (float*)d_out;
    float* attn = out + (size_t)B_ * L_ * D_;
    dim3 grid(B_ * (L_ / 64));   // 512
    dim3 block(256);
    hipLaunchKernelGGL(sdpa_kernel, grid, block, 0, stream, q, k, v, m, out, attn);
}

// Round 11
// 143.410 us; speedup vs baseline: 2.4222x; 1.2729x over previous
//
#include <hip/hip_runtime.h>
#include <hip/hip_bf16.h>
#include <math.h>

// ScaledDotProductAttention, masked_softmax semantics (clip ±15, mask-mult,
// exp(x - max), re-mask, /(sum+1e-6)). B=16, L=2048, D=64, TEMP=8.
//
// Round-11 = Round-7 kernel (best known, 176us) with ONE isolated change:
// attn + out stores are NON-TEMPORAL (global_store ... nt). Theory: cached
// stores of the 268MB attn walk the L3, evicting the L3-resident mask
// (explains FETCH=147MB < mask 268MB) and possibly costing write-allocate
// fills; nt stores bypass, leaving L3 to the single-read mask stream.

typedef __bf16 bf16x8v __attribute__((ext_vector_type(8)));
typedef __bf16 bf16x4v __attribute__((ext_vector_type(4)));
typedef __bf16 bf16x2v __attribute__((ext_vector_type(2)));
typedef float  f32x4   __attribute__((ext_vector_type(4)));
typedef int    i32x4   __attribute__((ext_vector_type(4)));

#define B_  16
#define L_  2048
#define D_  64
#define NKC 32

// swizzled byte offset within a [rows][64] bf16 tile (128 B per row)
__device__ __forceinline__ int swz(int row, int colb) {
    return (row * 128 + colb) ^ ((row & 7) << 4);
}
// swizzled byte offset within a [16 rows][64 f32] tile (256 B per row)
__device__ __forceinline__ int swzF(int row, int colb) {
    return row * 256 + (colb ^ ((row & 7) << 4));
}

// barrier WITHOUT the vmcnt(0) drain
__device__ __forceinline__ void bar() {
    asm volatile("s_waitcnt lgkmcnt(0)" ::: "memory");
    __builtin_amdgcn_s_barrier();
}

__global__ __launch_bounds__(256, 2)
void sdpa_kernel(const float* __restrict__ qg,
                 const float* __restrict__ kg,
                 const float* __restrict__ vg,
                 const int*   __restrict__ mg,
                 float* __restrict__ outg,    // [B][L][D]
                 float* __restrict__ attng)   // [B][L][L]
{
    __shared__ __align__(16) char KtB[2][8192];   // K tile bf16 [64][64] swz
    __shared__ __align__(16) char VtB[2][8192];   // V^T tile bf16 [d][k] swz
    __shared__ __align__(16) char PwB[4][2048];   // per-wave P bf16 [16][64] swz
    __shared__ __align__(16) char PfB[4][4096];   // per-wave P f32 [16][64] swzF
    __shared__ unsigned short Ml[NKC][256];       // mask bits [kc][thread]
    __shared__ unsigned Mn32[4][64];              // per-wave nibble xchg

    const int t  = threadIdx.x;
    const int w  = t >> 6;
    const int l  = t & 63;
    const int lq = l & 15;        // q within wave tile (MFMA col / A row)
    const int g  = l >> 4;        // 4-lane group

    // XCD-grouping remap: 512 blocks = 8 XCDs x 64
    const int bid  = blockIdx.x;
    const int virt = (bid & 7) * 64 + (bid >> 3);
    const int b  = virt >> 5;
    const int q0 = (virt & 31) * 64;
    const int qi = q0 + w * 16 + lq;

    const size_t kvbase = (size_t)b * (L_ * D_);
    const size_t qwrow  = (size_t)b * L_ + q0 + w * 16; // wave's first q row

    // ---- Q fragments (B operand), 1/8 temperature folded in ----
    bf16x8v qf0, qf1;
    {
        const float* qrow = qg + ((size_t)b * L_ + qi) * D_;
        const f32x4* p0 = (const f32x4*)(qrow + g * 8);
        const f32x4* p1 = (const f32x4*)(qrow + 32 + g * 8);
        f32x4 x0 = p0[0], x1 = p0[1], x2 = p1[0], x3 = p1[1];
        #pragma unroll
        for (int j = 0; j < 4; ++j) {
            qf0[j]     = (__bf16)(x0[j] * 0.125f);
            qf0[4 + j] = (__bf16)(x1[j] * 0.125f);
            qf1[j]     = (__bf16)(x2[j] * 0.125f);
            qf1[4 + j] = (__bf16)(x3[j] * 0.125f);
        }
    }

    // ---- staging geometry ----
    const int sr  = t >> 2;               // K-tile row this thread stages
    const int scb = (t & 3) * 32;         // byte col (16 bf16 = 32 B)
    const float* kbase  = kg + kvbase + (size_t)sr * D_ + (t & 3) * 16;
    const float* vbase0 = vg + kvbase + (size_t)(2 * (t & 31)) * D_ + (t >> 5) * 8;
    const int dg = t >> 5, kp = t & 31;
    // coalesced mask base: lane row = l>>4 (+4j), cols (l&15)*4
    const int* mbase = mg + (qwrow + (l >> 4)) * L_ + (l & 15) * 4;

    auto loadK = [&](int kc, f32x4& a, f32x4& bb, f32x4& c, f32x4& d) {
        const f32x4* s = (const f32x4*)(kbase + (size_t)kc * (64 * D_));
        a = s[0]; bb = s[1]; c = s[2]; d = s[3];
    };
    auto writeK = [&](char* buf, f32x4 a, f32x4 bb, f32x4 c, f32x4 d) {
        bf16x8v h0, h1;
        #pragma unroll
        for (int j = 0; j < 4; ++j) {
            h0[j] = (__bf16)a[j]; h0[4 + j] = (__bf16)bb[j];
            h1[j] = (__bf16)c[j]; h1[4 + j] = (__bf16)d[j];
        }
        *(bf16x8v*)(buf + swz(sr, scb))      = h0;
        *(bf16x8v*)(buf + swz(sr, scb + 16)) = h1;
    };
    auto loadV = [&](int kc, f32x4& a, f32x4& bb, f32x4& c, f32x4& d) {
        const float* r0 = vbase0 + (size_t)kc * (64 * D_);
        const f32x4* s0 = (const f32x4*)r0;
        const f32x4* s1 = (const f32x4*)(r0 + D_);
        a = s0[0]; bb = s0[1]; c = s1[0]; d = s1[1];
    };
    auto writeV = [&](char* buf, f32x4 a, f32x4 bb, f32x4 c, f32x4 d) {
        #pragma unroll
        for (int j = 0; j < 4; ++j) {
            bf16x2v p0; p0[0] = (__bf16)a[j];  p0[1] = (__bf16)c[j];
            *(bf16x2v*)(buf + swz(dg * 8 + j, kp * 4)) = p0;
            bf16x2v p1; p1[0] = (__bf16)bb[j]; p1[1] = (__bf16)d[j];
            *(bf16x2v*)(buf + swz(dg * 8 + 4 + j, kp * 4)) = p1;
        }
    };
    // coalesced mask load: 4 instrs, each 4 rows x 256B contiguous
    auto loadM = [&](int kc, i32x4& m0, i32x4& m1, i32x4& m2, i32x4& m3) {
        const int* p = mbase + kc * 64;
        m0 = *(const i32x4*)(p);
        m1 = *(const i32x4*)(p + 4 * L_);
        m2 = *(const i32x4*)(p + 8 * L_);
        m3 = *(const i32x4*)(p + 12 * L_);
    };

    float rS = 0.f;
    float inv = 0.f;

    auto compute1 = [&](const char* KB, int kc, i32x4 m0, i32x4 m1, i32x4 m2, i32x4 m3) {
        auto nib = [](i32x4 m) -> unsigned {
            return (m[0] ? 1u : 0u) | (m[1] ? 2u : 0u) | (m[2] ? 4u : 0u) | (m[3] ? 8u : 0u);
        };
        Mn32[w][l] = nib(m0) | (nib(m1) << 8) | (nib(m2) << 16) | (nib(m3) << 24);
        asm volatile("s_waitcnt lgkmcnt(0)" ::: "memory");  // same-wave xchg
        unsigned mbits = 0;
        const int sh = (lq >> 2) * 8;
        #pragma unroll
        for (int sub = 0; sub < 4; ++sub) {
            unsigned nb = (Mn32[w][(lq & 3) * 16 + sub * 4 + g] >> sh) & 0xFu;
            mbits |= nb << (sub * 4);
        }
        float part = 0.f;
        #pragma unroll
        for (int sub = 0; sub < 4; ++sub) {
            bf16x8v a0 = *(const bf16x8v*)(KB + swz(sub * 16 + lq, g * 16));
            bf16x8v a1 = *(const bf16x8v*)(KB + swz(sub * 16 + lq, 64 + g * 16));
            f32x4 s = {0.f, 0.f, 0.f, 0.f};
            s = __builtin_amdgcn_mfma_f32_16x16x32_bf16(a0, qf0, s, 0, 0, 0);
            s = __builtin_amdgcn_mfma_f32_16x16x32_bf16(a1, qf1, s, 0, 0, 0);
            #pragma unroll
            for (int r = 0; r < 4; ++r) {
                bool mm = (mbits >> (sub * 4 + r)) & 1u;
                float y = mm ? (fminf(fmaxf(s[r], -15.f), 15.f) - 15.f) : -1e30f;
                part += __expf(y);        // exp(-1e30) = 0
            }
        }
        rS += part;
        Ml[kc][t] = (unsigned short)mbits;
    };

    f32x4 acc[4];
    #pragma unroll
    for (int i = 0; i < 4; ++i) acc[i] = (f32x4){0.f, 0.f, 0.f, 0.f};

    auto compute2 = [&](const char* KB, const char* VB, int kc) {
        const unsigned mbits = Ml[kc][t];
        char* PFw = PfB[w];
        #pragma unroll
        for (int sub = 0; sub < 4; ++sub) {
            bf16x8v a0 = *(const bf16x8v*)(KB + swz(sub * 16 + lq, g * 16));
            bf16x8v a1 = *(const bf16x8v*)(KB + swz(sub * 16 + lq, 64 + g * 16));
            f32x4 s = {0.f, 0.f, 0.f, 0.f};
            s = __builtin_amdgcn_mfma_f32_16x16x32_bf16(a0, qf0, s, 0, 0, 0);
            s = __builtin_amdgcn_mfma_f32_16x16x32_bf16(a1, qf1, s, 0, 0, 0);
            f32x4 pv; bf16x4v pb;
            #pragma unroll
            for (int r = 0; r < 4; ++r) {
                bool mm = (mbits >> (sub * 4 + r)) & 1u;
                float y = mm ? (fminf(fmaxf(s[r], -15.f), 15.f) - 15.f) : -1e30f;
                float p = __expf(y) * inv;
                pv[r] = p; pb[r] = (__bf16)p;
            }
            *(f32x4*)(PFw + swzF(lq, (sub * 16 + g * 4) * 4)) = pv;   // f32 stage
            *(bf16x4v*)(PwB[w] + swz(lq, (sub * 16 + g * 4) * 2)) = pb;
        }
        // PV MFMAs (same-wave LDS RAW)
        #pragma unroll
        for (int ks = 0; ks < 2; ++ks) {
            bf16x8v pa = *(const bf16x8v*)(PwB[w] + swz(lq, ks * 64 + g * 16));
            #pragma unroll
            for (int dt = 0; dt < 4; ++dt) {
                bf16x8v vb = *(const bf16x8v*)(VB + swz(dt * 16 + lq, ks * 64 + g * 16));
                acc[dt] = __builtin_amdgcn_mfma_f32_16x16x32_bf16(pa, vb, acc[dt], 0, 0, 0);
            }
        }
        // coalesced NON-TEMPORAL attn store: 4 instrs x (4 rows x 256 B)
        #pragma unroll
        for (int j = 0; j < 4; ++j) {
            const int row = (l >> 4) + 4 * j;
            const int col = (l & 15) * 4;
            f32x4 o = *(const f32x4*)(PFw + swzF(row, col * 4));
            __builtin_nontemporal_store(o, (f32x4*)(attng + (qwrow + row) * L_ + kc * 64 + col));
        }
    };

    // prefetch register sets (A = even tiles, B = odd tiles)
    f32x4 kA0, kA1, kA2, kA3, kB0, kB1, kB2, kB3;
    f32x4 vA0, vA1, vA2, vA3, vB0, vB1, vB2, vB3;
    i32x4 mA0, mA1, mA2, mA3, mB0, mB1, mB2, mB3;

    // ======================= PASS 1: masked exp-sum =======================
    loadK(0, kA0, kA1, kA2, kA3);
    loadM(0, mA0, mA1, mA2, mA3);
    writeK(KtB[0], kA0, kA1, kA2, kA3);      // one-time stall
    loadK(1, kB0, kB1, kB2, kB3);
    loadM(1, mB0, mB1, mB2, mB3);
    bar();
    #pragma unroll 1
    for (int kc = 0; kc < NKC; kc += 2) {
        { int kn = (kc + 2 < NKC) ? kc + 2 : NKC - 1; loadK(kn, kA0, kA1, kA2, kA3); }
        compute1(KtB[0], kc, mA0, mA1, mA2, mA3);
        { int kn = (kc + 2 < NKC) ? kc + 2 : NKC - 1; loadM(kn, mA0, mA1, mA2, mA3); }
        writeK(KtB[1], kB0, kB1, kB2, kB3);
        bar();
        { int kn = (kc + 3 < NKC) ? kc + 3 : NKC - 1; loadK(kn, kB0, kB1, kB2, kB3); }
        compute1(KtB[1], kc + 1, mB0, mB1, mB2, mB3);
        { int kn = (kc + 3 < NKC) ? kc + 3 : NKC - 1; loadM(kn, mB0, mB1, mB2, mB3); }
        writeK(KtB[0], kA0, kA1, kA2, kA3);
        bar();
    }

    // issue pass-2 first tiles, then reduce (overlap load latency)
    loadK(0, kA0, kA1, kA2, kA3);
    loadV(0, vA0, vA1, vA2, vA3);
    rS += __shfl_xor(rS, 16, 64);
    rS += __shfl_xor(rS, 32, 64);
    inv = 1.f / (rS + 1e-6f);

    // ======================= PASS 2: attn + PV =======================
    writeK(KtB[0], kA0, kA1, kA2, kA3);
    writeV(VtB[0], vA0, vA1, vA2, vA3);
    loadK(1, kB0, kB1, kB2, kB3);
    loadV(1, vB0, vB1, vB2, vB3);
    bar();
    #pragma unroll 1
    for (int kc = 0; kc < NKC; kc += 2) {
        { int kn = (kc + 2 < NKC) ? kc + 2 : NKC - 1;
          loadK(kn, kA0, kA1, kA2, kA3); loadV(kn, vA0, vA1, vA2, vA3); }
        compute2(KtB[0], VtB[0], kc);
        writeK(KtB[1], kB0, kB1, kB2, kB3);
        writeV(VtB[1], vB0, vB1, vB2, vB3);
        bar();
        { int kn = (kc + 3 < NKC) ? kc + 3 : NKC - 1;
          loadK(kn, kB0, kB1, kB2, kB3); loadV(kn, vB0, vB1, vB2, vB3); }
        compute2(KtB[1], VtB[1], kc + 1);
        writeK(KtB[0], kA0, kA1, kA2, kA3);
        writeV(VtB[0], vA0, vA1, vA2, vA3);
        bar();
    }

    // epilogue: acc row = q-local (g*4+r), col = d (dt*16+lq); NT stores
    #pragma unroll
    for (int dt = 0; dt < 4; ++dt) {
        #pragma unroll
        for (int r = 0; r < 4; ++r) {
            __builtin_nontemporal_store(acc[dt][r],
                outg + ((size_t)b * L_ + (q0 + w * 16 + g * 4 + r)) * D_ + dt * 16 + lq);
        }
    }
}

extern "C" void kernel_launch(void* const* d_in, const int* in_sizes, int n_in,
                              void* d_out, int out_size, void* d_ws, size_t ws_size,
                              hipStream_t stream) {
    (void)in_sizes; (void)n_in; (void)out_size; (void)d_ws; (void)ws_size;
    const float* q = (const float*)d_in[0];
    const float* k = (const float*)d_in[1];
    const float* v = (const float*)d_in[2];
    const int*   m = (const int*)d_in[3];
    float* out  = (float*)d_out;
    float* attn = out + (size_t)B_ * L_ * D_;
    dim3 grid(B_ * (L_ / 64));   // 512
    dim3 block(256);
    hipLaunchKernelGGL(sdpa_kernel, grid, block, 0, stream, q, k, v, m, out, attn);
}